// Round 1
// baseline (10895.156 us; speedup 1.0000x reference)
//
#include <hip/hip_runtime.h>
#include <math.h>

// GRU_32564442038643 — round 1: correctness-first batch-parallel persistent kernel.
// B=256 workgroups (one per batch row, no grid sync needed: recurrence is
// batch-independent). Weights converted to bf16 once per call, streamed from L2.

#define BATCH  256
#define SEQ    512
#define INPUT  256
#define HIDDEN 256
#define DTOT   512   // INPUT + HIDDEN

__device__ __forceinline__ float bf2f(unsigned short u) {
    return __uint_as_float(((unsigned int)u) << 16);
}
__device__ __forceinline__ unsigned short f2bf(float f) {
    unsigned int u = __float_as_uint(f);
    u += 0x7FFFu + ((u >> 16) & 1u);   // round-to-nearest-even
    return (unsigned short)(u >> 16);
}

__device__ __forceinline__ float ldw(const unsigned short* p) { return bf2f(*p); }
__device__ __forceinline__ float ldw(const float* p)          { return *p; }

// Convert the three [DTOT, HIDDEN] fp32 weight matrices to bf16 into d_ws.
__global__ __launch_bounds__(256) void prep_weights_k(
    const float* __restrict__ Wr,
    const float* __restrict__ Wz,
    const float* __restrict__ Wh,
    unsigned short* __restrict__ W16)
{
    const int n = DTOT * HIDDEN;
    int idx = blockIdx.x * 256 + threadIdx.x;
    if (idx >= 3 * n) return;
    int m = idx / n;
    int r = idx - m * n;
    const float* src = (m == 0) ? Wr : ((m == 1) ? Wz : Wh);
    W16[idx] = f2bf(src[r]);
}

// One workgroup per batch row; thread j owns gate column j.
// LDS: xh = [x_t | h], xrh = [x_t | r*h]. 3 barriers per step.
template <typename WT>
__global__ __launch_bounds__(256) void gru_seq_k(
    const float* __restrict__ x,
    const WT* __restrict__ Wr,
    const WT* __restrict__ Wz,
    const WT* __restrict__ Wh,
    const float* __restrict__ br,
    const float* __restrict__ bz,
    const float* __restrict__ bh,
    const float* __restrict__ Wo,
    const float* __restrict__ bo,
    float* __restrict__ out)
{
    const int b = blockIdx.x;
    const int j = threadIdx.x;

    __shared__ float xh[DTOT];    // [x_t (0:256) | h (256:512)]
    __shared__ float xrh[DTOT];   // [x_t (0:256) | r*h (256:512)]

    xh[INPUT + j] = 0.0f;         // h0 = 0

    const float brj = br[j];
    const float bzj = bz[j];
    const float bhj = bh[j];

    const float* xb  = x + (size_t)b * SEQ * INPUT;
    const WT* wrj = Wr + j;       // column j, stride HIDDEN
    const WT* wzj = Wz + j;
    const WT* whj = Wh + j;

    __syncthreads();

    for (int t = 0; t < SEQ; ++t) {
        float xv = xb[t * INPUT + j];
        xh[j]  = xv;
        xrh[j] = xv;
        __syncthreads();   // (1) x_t + h visible

        // Gates r, z: preact = [x_t|h] @ W + b  (column j)
        float ar = brj, az = bzj;
        #pragma unroll 8
        for (int k = 0; k < DTOT; ++k) {
            float v = xh[k];   // wave-uniform -> LDS broadcast
            ar += v * ldw(wrj + k * HIDDEN);
            az += v * ldw(wzj + k * HIDDEN);
        }
        float rg = 1.0f / (1.0f + __expf(-ar));
        float zg = 1.0f / (1.0f + __expf(-az));
        float hj = xh[INPUT + j];
        xrh[INPUT + j] = rg * hj;
        __syncthreads();   // (2) r*h visible

        // Candidate: tanh([x_t | r*h] @ Wh + bh)
        float ah = bhj;
        #pragma unroll 8
        for (int k = 0; k < DTOT; ++k) {
            ah += xrh[k] * ldw(whj + k * HIDDEN);
        }
        float hc = tanhf(ah);
        float hn = zg * hj + (1.0f - zg) * hc;
        xh[INPUT + j] = hn;   // only thread j touches h[j] until barrier (3)
        __syncthreads();   // (3) new h visible; also fences xrh reads vs next-step writes
    }

    // Epilogue: out[b,:] = h_last @ Wo + bo
    float acc = bo[j];
    #pragma unroll 8
    for (int k = 0; k < HIDDEN; ++k) {
        acc += xh[INPUT + k] * Wo[k * HIDDEN + j];
    }
    out[(size_t)b * HIDDEN + j] = acc;
}

extern "C" void kernel_launch(void* const* d_in, const int* in_sizes, int n_in,
                              void* d_out, int out_size, void* d_ws, size_t ws_size,
                              hipStream_t stream) {
    const float* x  = (const float*)d_in[0];
    const float* Wr = (const float*)d_in[1];
    const float* br = (const float*)d_in[2];
    const float* Wz = (const float*)d_in[3];
    const float* bz = (const float*)d_in[4];
    const float* Wh = (const float*)d_in[5];
    const float* bh = (const float*)d_in[6];
    const float* Wo = (const float*)d_in[7];
    const float* bo = (const float*)d_in[8];
    float* out = (float*)d_out;

    const size_t n = (size_t)DTOT * HIDDEN;
    const size_t need = 3 * n * sizeof(unsigned short);

    if (ws_size >= need) {
        unsigned short* W16 = (unsigned short*)d_ws;
        prep_weights_k<<<(int)((3 * n + 255) / 256), 256, 0, stream>>>(Wr, Wz, Wh, W16);
        gru_seq_k<unsigned short><<<BATCH, 256, 0, stream>>>(
            x, W16, W16 + n, W16 + 2 * n, br, bz, bh, Wo, bo, out);
    } else {
        // Fallback: stream fp32 weights directly (2x L2 bytes, still correct).
        gru_seq_k<float><<<BATCH, 256, 0, stream>>>(
            x, Wr, Wz, Wh, br, bz, bh, Wo, bo, out);
    }
}

// Round 2
// 2162.381 us; speedup vs baseline: 5.0385x; 5.0385x over previous
//
#include <hip/hip_runtime.h>
#include <math.h>

// GRU_32564442038643 — round 2: MFMA path.
//   pack_weights_k : fragment-pack Wx/Wh-parts + Wo to bf16 in ws
//   xgemm_k        : X[t,b,:] = x_t @ Wx + bias (all gates), bf16 frag-packed, 201 MB
//   gru_rec_k      : 16 WGs x 8 waves; h-part weights register-resident (192 VGPR/lane);
//                    per step: phase A (r,z MFMA K=256) -> elementwise -> phase B (cand).
// Fallback to round-1 scalar kernel if ws_size too small.

#define BATCH  256
#define SEQ    512
#define INPUT  256
#define HIDDEN 256
#define DTOT   512
#define NT     48     // n-tiles over N=768 (r|z|h)
#define NT_O   16     // n-tiles over N=256 (Wo)

typedef float          f32x4 __attribute__((ext_vector_type(4)));
typedef short          s16x8 __attribute__((ext_vector_type(8)));
typedef unsigned short u16x8 __attribute__((ext_vector_type(8)));
typedef unsigned int   u32x2 __attribute__((ext_vector_type(2)));

// ws layout (bytes)
#define WH_OFF   0u            // 393216: h-part of [Wr|Wz|Wh] frag-packed bf16
#define WX_OFF   393216u       // 393216: x-part
#define WO_OFF   786432u       // 131072: Wo
#define X_OFF    917504u       // 201326592: X (bf16, frag-packed per (t,g,nt,lane))
#define WS_NEED     (917504ull + 201326592ull)
#define WS_NEED_OLD 786432ull

__device__ __forceinline__ unsigned short f2bf(float f) {
    unsigned int u = __float_as_uint(f);
    u += 0x7FFFu + ((u >> 16) & 1u);   // RNE
    return (unsigned short)(u >> 16);
}
__device__ __forceinline__ float bf2f(unsigned short u) {
    return __uint_as_float(((unsigned int)u) << 16);
}
__device__ __forceinline__ float sigm(float x) {
    x = fminf(fmaxf(x, -30.f), 30.f);
    return 1.f / (1.f + __expf(-x));
}
__device__ __forceinline__ float ftanh(float x) {
    x = fminf(fmaxf(x, -15.f), 15.f);
    float e = __expf(2.f * x);
    return (e - 1.f) / (e + 1.f);
}
__device__ __forceinline__ f32x4 cvt4(u32x2 u) {
    f32x4 a;
    a[0] = __uint_as_float(u[0] << 16);
    a[1] = __uint_as_float(u[0] & 0xffff0000u);
    a[2] = __uint_as_float(u[1] << 16);
    a[3] = __uint_as_float(u[1] & 0xffff0000u);
    return a;
}

// ---------------- weight packing ----------------
// Fragment (kt,nt), lane l: 8 bf16 = W[k = kt*32 + (l>>4)*8 + j][n = nt*16 + (l&15)]
__global__ __launch_bounds__(256) void pack_weights_k(
    const float* __restrict__ Wr, const float* __restrict__ Wz,
    const float* __restrict__ Wh, const float* __restrict__ Wo,
    unsigned short* __restrict__ ws)
{
    int tid = blockIdx.x * 256 + threadIdx.x;   // 0..57343
    int tile = tid >> 6;
    int l = tid & 63, quad = l >> 4, lan = l & 15;
    u16x8 v;
    unsigned short* dst;
    if (tile < 768) {
        int isH = tile < 384;                   // first 384 tiles: h-part
        int t2 = isH ? tile : tile - 384;       // t2 = kt*48 + nt
        int kt = t2 / NT, nt = t2 % NT;
        int n = nt * 16 + lan, gate = n >> 8, col = n & 255;
        const float* W = gate == 0 ? Wr : (gate == 1 ? Wz : Wh);
        int kbase = kt * 32 + quad * 8 + (isH ? 256 : 0);
        #pragma unroll
        for (int j = 0; j < 8; ++j) v[j] = f2bf(W[(kbase + j) * 256 + col]);
        dst = (unsigned short*)((char*)ws + (isH ? WH_OFF : WX_OFF)) + (size_t)(t2 * 64 + l) * 8;
    } else {
        int t2 = tile - 768;                    // t2 = kt*16 + nt
        int kt = t2 / NT_O, nt = t2 % NT_O;
        int col = nt * 16 + lan;
        int kbase = kt * 32 + quad * 8;
        #pragma unroll
        for (int j = 0; j < 8; ++j) v[j] = f2bf(Wo[(kbase + j) * 256 + col]);
        dst = (unsigned short*)((char*)ws + WO_OFF) + (size_t)(t2 * 64 + l) * 8;
    }
    *(u16x8*)dst = v;
}

// ---------------- X precompute ----------------
// 256 WGs x 512 thr (8 waves, 2/SIMD). Wave owns nt = wave + 8i, i=0..5.
// Wx frags register-resident; loop 32 (t,g) units per WG.
__global__ __launch_bounds__(512, 2) void xgemm_k(
    const float* __restrict__ x,
    const float* __restrict__ br, const float* __restrict__ bz, const float* __restrict__ bh,
    unsigned short* __restrict__ ws)
{
    __shared__ __align__(16) unsigned short Xb[16][264];
    const int th = threadIdx.x, wave = th >> 6, l = th & 63, quad = l >> 4, lan = l & 15;
    const s16x8* WX = (const s16x8*)((char*)ws + WX_OFF);
    s16x8 wf[6][8];
    #pragma unroll
    for (int i = 0; i < 6; ++i) {
        int nt = wave + 8 * i;
        #pragma unroll
        for (int kt = 0; kt < 8; ++kt) wf[i][kt] = WX[(kt * NT + nt) * 64 + l];
    }
    float bias[6];
    #pragma unroll
    for (int i = 0; i < 6; ++i) {
        int n = (wave + 8 * i) * 16 + lan;
        const float* bb = n < 256 ? br : (n < 512 ? bz : bh);
        bias[i] = bb[n & 255];
    }
    u32x2* Xout = (u32x2*)((char*)ws + X_OFF);
    for (int u = 0; u < 32; ++u) {
        int unit = blockIdx.x * 32 + u;         // unit = t*16 + g
        int t = unit >> 4, g = unit & 15;
        {   // stage 16 rows of x_t as bf16
            int row = th >> 5, seg = th & 31;
            const float* src = x + ((size_t)(g * 16 + row) * SEQ + t) * INPUT + seg * 8;
            f32x4 a = *(const f32x4*)src;
            f32x4 b = *(const f32x4*)(src + 4);
            u16x8 p;
            p[0] = f2bf(a[0]); p[1] = f2bf(a[1]); p[2] = f2bf(a[2]); p[3] = f2bf(a[3]);
            p[4] = f2bf(b[0]); p[5] = f2bf(b[1]); p[6] = f2bf(b[2]); p[7] = f2bf(b[3]);
            *(u16x8*)&Xb[row][seg * 8] = p;
        }
        __syncthreads();
        f32x4 acc[6];
        #pragma unroll
        for (int i = 0; i < 6; ++i) { acc[i][0] = bias[i]; acc[i][1] = bias[i]; acc[i][2] = bias[i]; acc[i][3] = bias[i]; }
        #pragma unroll
        for (int kt = 0; kt < 8; ++kt) {
            s16x8 a = *(const s16x8*)&Xb[lan][kt * 32 + quad * 8];
            #pragma unroll
            for (int i = 0; i < 6; ++i)
                acc[i] = __builtin_amdgcn_mfma_f32_16x16x32_bf16(a, wf[i][kt], acc[i], 0, 0, 0);
        }
        #pragma unroll
        for (int i = 0; i < 6; ++i) {
            int nt = wave + 8 * i;
            u32x2 p;
            p[0] = (unsigned)f2bf(acc[i][0]) | ((unsigned)f2bf(acc[i][1]) << 16);
            p[1] = (unsigned)f2bf(acc[i][2]) | ((unsigned)f2bf(acc[i][3]) << 16);
            Xout[((size_t)unit * NT + nt) * 64 + l] = p;
        }
        __syncthreads();   // Xb reads done before next unit's staging writes
    }
}

// ---------------- recurrence ----------------
// 16 WGs x 512 thr. WG g owns batch rows 16g..16g+15. Weights in registers.
__global__ __launch_bounds__(512, 2) void gru_rec_k(
    const float* __restrict__ bo,
    unsigned short* __restrict__ ws,
    float* __restrict__ out)
{
    __shared__ __align__(16) unsigned short Hb[16][264];   // h as bf16 (MFMA A)
    __shared__ __align__(16) unsigned short RHb[16][264];  // r*h as bf16 (MFMA A)
    __shared__ float Hf[16][260];                          // h fp32 (elementwise)
    __shared__ float Zf[16][260];                          // z fp32
    const int th = threadIdx.x, wave = th >> 6, l = th & 63, quad = l >> 4, lan = l & 15;
    const int g = blockIdx.x;
    const s16x8* WH = (const s16x8*)((char*)ws + WH_OFF);
    s16x8 wf[6][8];                                        // 192 VGPR: persistent weights
    #pragma unroll
    for (int i = 0; i < 6; ++i) {
        int nt = wave + 8 * i;
        #pragma unroll
        for (int kt = 0; kt < 8; ++kt) wf[i][kt] = WH[(kt * NT + nt) * 64 + l];
    }
    for (int idx = th; idx < 16 * 264; idx += 512) ((unsigned short*)Hb)[idx] = 0;
    for (int idx = th; idx < 16 * 260; idx += 512) ((float*)Hf)[idx] = 0.f;
    const u32x2* Xp = (const u32x2*)((char*)ws + X_OFF);
    __syncthreads();

    for (int t = 0; t < SEQ; ++t) {
        const size_t ub = ((size_t)(t * 16 + g)) * NT * 64;
        // ---- phase A: r,z preacts (nt = wave+8i, i<4 -> nt<32), A = h ----
        u32x2 xf[4];
        #pragma unroll
        for (int i = 0; i < 4; ++i) xf[i] = Xp[ub + (size_t)(wave + 8 * i) * 64 + l];
        f32x4 acc[4];
        #pragma unroll
        for (int i = 0; i < 4; ++i) acc[i] = cvt4(xf[i]);
        #pragma unroll
        for (int kt = 0; kt < 8; ++kt) {
            s16x8 a = *(const s16x8*)&Hb[lan][kt * 32 + quad * 8];
            #pragma unroll
            for (int i = 0; i < 4; ++i)
                acc[i] = __builtin_amdgcn_mfma_f32_16x16x32_bf16(a, wf[i][kt], acc[i], 0, 0, 0);
        }
        #pragma unroll
        for (int i = 0; i < 4; ++i) {
            int nt = wave + 8 * i;
            int n = nt * 16 + lan;                 // wave-uniform gate split (nt<16 vs not)
            if (n < 256) {
                #pragma unroll
                for (int r = 0; r < 4; ++r) {
                    int row = quad * 4 + r;
                    float rh = sigm(acc[i][r]) * Hf[row][n];
                    RHb[row][n] = f2bf(rh);
                }
            } else {
                #pragma unroll
                for (int r = 0; r < 4; ++r) {
                    int row = quad * 4 + r;
                    Zf[row][n - 256] = sigm(acc[i][r]);
                }
            }
        }
        __syncthreads();
        // ---- phase B: candidate (nt = wave+8i, i=4,5), A = r*h ----
        u32x2 xf2[2];
        #pragma unroll
        for (int i = 0; i < 2; ++i) xf2[i] = Xp[ub + (size_t)(wave + 8 * (4 + i)) * 64 + l];
        f32x4 accB[2];
        #pragma unroll
        for (int i = 0; i < 2; ++i) accB[i] = cvt4(xf2[i]);
        #pragma unroll
        for (int kt = 0; kt < 8; ++kt) {
            s16x8 a = *(const s16x8*)&RHb[lan][kt * 32 + quad * 8];
            #pragma unroll
            for (int i = 0; i < 2; ++i)
                accB[i] = __builtin_amdgcn_mfma_f32_16x16x32_bf16(a, wf[4 + i][kt], accB[i], 0, 0, 0);
        }
        #pragma unroll
        for (int i = 0; i < 2; ++i) {
            int col = (wave + 8 * (4 + i)) * 16 + lan - 512;
            #pragma unroll
            for (int r = 0; r < 4; ++r) {
                int row = quad * 4 + r;
                float hc = ftanh(accB[i][r]);
                float zz = Zf[row][col];
                float hn = zz * Hf[row][col] + (1.f - zz) * hc;
                Hf[row][col] = hn;
                Hb[row][col] = f2bf(hn);
            }
        }
        __syncthreads();
    }
    // ---- epilogue: out = h_last @ Wo + bo ----
    const s16x8* WO = (const s16x8*)((char*)ws + WO_OFF);
    #pragma unroll
    for (int io = 0; io < 2; ++io) {
        int nt = wave + 8 * io;
        int col = nt * 16 + lan;
        float bv = bo[col];
        f32x4 acc;
        acc[0] = bv; acc[1] = bv; acc[2] = bv; acc[3] = bv;
        #pragma unroll
        for (int kt = 0; kt < 8; ++kt) {
            s16x8 a = *(const s16x8*)&Hb[lan][kt * 32 + quad * 8];
            acc = __builtin_amdgcn_mfma_f32_16x16x32_bf16(a, WO[(kt * NT_O + nt) * 64 + l], acc, 0, 0, 0);
        }
        #pragma unroll
        for (int r = 0; r < 4; ++r)
            out[(size_t)(g * 16 + quad * 4 + r) * 256 + col] = acc[r];
    }
}

// ---------------- round-1 fallback (known correct, 10.9 ms) ----------------
__global__ __launch_bounds__(256) void prep_weights_k(
    const float* __restrict__ Wr, const float* __restrict__ Wz,
    const float* __restrict__ Wh, unsigned short* __restrict__ W16)
{
    const int n = DTOT * HIDDEN;
    int idx = blockIdx.x * 256 + threadIdx.x;
    if (idx >= 3 * n) return;
    int m = idx / n;
    int r = idx - m * n;
    const float* src = (m == 0) ? Wr : ((m == 1) ? Wz : Wh);
    W16[idx] = f2bf(src[r]);
}

__device__ __forceinline__ float ldw(const unsigned short* p) { return bf2f(*p); }
__device__ __forceinline__ float ldw(const float* p)          { return *p; }

template <typename WT>
__global__ __launch_bounds__(256) void gru_seq_k(
    const float* __restrict__ x,
    const WT* __restrict__ Wr, const WT* __restrict__ Wz, const WT* __restrict__ Wh,
    const float* __restrict__ br, const float* __restrict__ bz, const float* __restrict__ bh,
    const float* __restrict__ Wo, const float* __restrict__ bo,
    float* __restrict__ out)
{
    const int b = blockIdx.x, j = threadIdx.x;
    __shared__ float xh[DTOT];
    __shared__ float xrh[DTOT];
    xh[INPUT + j] = 0.0f;
    const float brj = br[j], bzj = bz[j], bhj = bh[j];
    const float* xb = x + (size_t)b * SEQ * INPUT;
    const WT* wrj = Wr + j;
    const WT* wzj = Wz + j;
    const WT* whj = Wh + j;
    __syncthreads();
    for (int t = 0; t < SEQ; ++t) {
        float xv = xb[t * INPUT + j];
        xh[j] = xv; xrh[j] = xv;
        __syncthreads();
        float ar = brj, az = bzj;
        #pragma unroll 8
        for (int k = 0; k < DTOT; ++k) {
            float v = xh[k];
            ar += v * ldw(wrj + k * HIDDEN);
            az += v * ldw(wzj + k * HIDDEN);
        }
        float rg = 1.0f / (1.0f + __expf(-ar));
        float zg = 1.0f / (1.0f + __expf(-az));
        float hj = xh[INPUT + j];
        xrh[INPUT + j] = rg * hj;
        __syncthreads();
        float ah = bhj;
        #pragma unroll 8
        for (int k = 0; k < DTOT; ++k) ah += xrh[k] * ldw(whj + k * HIDDEN);
        float hc = tanhf(ah);
        float hn = zg * hj + (1.0f - zg) * hc;
        xh[INPUT + j] = hn;
        __syncthreads();
    }
    float acc = bo[j];
    #pragma unroll 8
    for (int k = 0; k < HIDDEN; ++k) acc += xh[INPUT + k] * Wo[k * HIDDEN + j];
    out[(size_t)b * HIDDEN + j] = acc;
}

extern "C" void kernel_launch(void* const* d_in, const int* in_sizes, int n_in,
                              void* d_out, int out_size, void* d_ws, size_t ws_size,
                              hipStream_t stream) {
    const float* x  = (const float*)d_in[0];
    const float* Wr = (const float*)d_in[1];
    const float* br = (const float*)d_in[2];
    const float* Wz = (const float*)d_in[3];
    const float* bz = (const float*)d_in[4];
    const float* Wh = (const float*)d_in[5];
    const float* bh = (const float*)d_in[6];
    const float* Wo = (const float*)d_in[7];
    const float* bo = (const float*)d_in[8];
    float* out = (float*)d_out;

    if (ws_size >= WS_NEED) {
        unsigned short* ws = (unsigned short*)d_ws;
        pack_weights_k<<<224, 256, 0, stream>>>(Wr, Wz, Wh, Wo, ws);
        xgemm_k<<<256, 512, 0, stream>>>(x, br, bz, bh, ws);
        gru_rec_k<<<16, 512, 0, stream>>>(bo, ws, out);
    } else if (ws_size >= WS_NEED_OLD) {
        unsigned short* W16 = (unsigned short*)d_ws;
        const size_t n = (size_t)DTOT * HIDDEN;
        prep_weights_k<<<(int)((3 * n + 255) / 256), 256, 0, stream>>>(Wr, Wz, Wh, W16);
        gru_seq_k<unsigned short><<<BATCH, 256, 0, stream>>>(
            x, W16, W16 + n, W16 + 2 * n, br, bz, bh, Wo, bo, out);
    } else {
        gru_seq_k<float><<<BATCH, 256, 0, stream>>>(
            x, Wr, Wz, Wh, br, bz, bh, Wo, bo, out);
    }
}

// Round 3
// 1635.636 us; speedup vs baseline: 6.6611x; 1.3220x over previous
//
#include <hip/hip_runtime.h>
#include <math.h>

// GRU_32564442038643 — round 3.
//  R2 post-mortem: VGPR_Count=128 under launch_bounds(512,2) => compiler demoted the
//  192-VGPR weight fragments to per-step L2 reloads (~3.2TB over the kernel, ~103GB/s/CU,
//  invisible in FETCH_SIZE). Fix: 256thr/WG @ 1 wave/SIMD (512-reg budget) so all 96
//  fragments (384 VGPR) are truly resident; z/h carried in registers via nt-triple
//  ownership; X prefetched one step ahead into registers; exp2-scaled weights.

#define BATCH  256
#define SEQ    512
#define INPUT  256
#define HIDDEN 256
#define DTOT   512
#define NT     48
#define NT_O   16
#define LOG2E  1.44269504088896f

typedef float          f32x4 __attribute__((ext_vector_type(4)));
typedef short          s16x8 __attribute__((ext_vector_type(8)));
typedef unsigned short u16x8 __attribute__((ext_vector_type(8)));
typedef unsigned int   u32x2 __attribute__((ext_vector_type(2)));

// ws layout (bytes)
#define WH_OFF   0u            // 393216: h-part of [Wr|Wz|Wh], frag-packed bf16 (exp2-scaled)
#define WX_OFF   393216u       // 393216: x-part (exp2-scaled)
#define WO_OFF   786432u       // 131072: Wo (unscaled)
#define X_OFF    917504u       // 201326592: X = x@Wx + b (scaled), bf16 frag-packed
#define WS_NEED     (917504ull + 201326592ull)
#define WS_NEED_OLD 786432ull

__device__ __forceinline__ unsigned short f2bf(float f) {        // RNE (pack path)
    unsigned int u = __float_as_uint(f);
    u += 0x7FFFu + ((u >> 16) & 1u);
    return (unsigned short)(u >> 16);
}
__device__ __forceinline__ unsigned short f2bf_fast(float f) {   // round-nearest, 2 instr
    return (unsigned short)((__float_as_uint(f) + 0x8000u) >> 16);
}
__device__ __forceinline__ float bf2f(unsigned short u) {
    return __uint_as_float(((unsigned int)u) << 16);
}
__device__ __forceinline__ f32x4 cvt4(u32x2 u) {
    f32x4 a;
    a[0] = __uint_as_float(u[0] << 16);
    a[1] = __uint_as_float(u[0] & 0xffff0000u);
    a[2] = __uint_as_float(u[1] << 16);
    a[3] = __uint_as_float(u[1] & 0xffff0000u);
    return a;
}
#if __has_builtin(__builtin_amdgcn_exp2f)
#define EXP2F(x) __builtin_amdgcn_exp2f(x)
#else
#define EXP2F(x) exp2f(x)
#endif
#if __has_builtin(__builtin_amdgcn_rcpf)
#define RCPF(x) __builtin_amdgcn_rcpf(x)
#else
#define RCPF(x) (1.0f / (x))
#endif

// ---------------- weight packing (with exp2 gate scaling) ----------------
// Fragment (kt,nt), lane l: 8 bf16 = W[k = kt*32 + (l>>4)*8 + j][n = nt*16 + (l&15)]
__global__ __launch_bounds__(256) void pack_weights_k(
    const float* __restrict__ Wr, const float* __restrict__ Wz,
    const float* __restrict__ Wh, const float* __restrict__ Wo,
    unsigned short* __restrict__ ws)
{
    int tid = blockIdx.x * 256 + threadIdx.x;   // 0..57343
    int tile = tid >> 6;
    int l = tid & 63, quad = l >> 4, lan = l & 15;
    u16x8 v;
    unsigned short* dst;
    if (tile < 768) {
        int isH = tile < 384;
        int t2 = isH ? tile : tile - 384;       // t2 = kt*48 + nt
        int kt = t2 / NT, nt = t2 % NT;
        int n = nt * 16 + lan, gate = n >> 8, col = n & 255;
        const float* W = gate == 0 ? Wr : (gate == 1 ? Wz : Wh);
        float scale = (gate == 2) ? 2.f * LOG2E : LOG2E;   // fold exp->exp2 scaling
        int kbase = kt * 32 + quad * 8 + (isH ? 256 : 0);
        #pragma unroll
        for (int j = 0; j < 8; ++j) v[j] = f2bf(W[(kbase + j) * 256 + col] * scale);
        dst = (unsigned short*)((char*)ws + (isH ? WH_OFF : WX_OFF)) + (size_t)(t2 * 64 + l) * 8;
    } else {
        int t2 = tile - 768;                    // t2 = kt*16 + nt
        int kt = t2 / NT_O, nt = t2 % NT_O;
        int col = nt * 16 + lan;
        int kbase = kt * 32 + quad * 8;
        #pragma unroll
        for (int j = 0; j < 8; ++j) v[j] = f2bf(Wo[(kbase + j) * 256 + col]);
        dst = (unsigned short*)((char*)ws + WO_OFF) + (size_t)(t2 * 64 + l) * 8;
    }
    *(u16x8*)dst = v;
}

// ---------------- X precompute (streamed weights by design) ----------------
// 512 WGs x 512 thr; 16 (t,g) units per WG. Wave owns nt = wave + 8i, i<6.
__global__ __launch_bounds__(512, 2) void xgemm_k(
    const float* __restrict__ x,
    const float* __restrict__ br, const float* __restrict__ bz, const float* __restrict__ bh,
    unsigned short* __restrict__ ws)
{
    __shared__ __align__(16) unsigned short Xb[16][264];
    const int th = threadIdx.x, wave = th >> 6, l = th & 63, quad = l >> 4, lan = l & 15;
    const s16x8* WX = (const s16x8*)((char*)ws + WX_OFF);
    float bias[6];
    #pragma unroll
    for (int i = 0; i < 6; ++i) {
        int n = (wave + 8 * i) * 16 + lan;
        const float* bb = n < 256 ? br : (n < 512 ? bz : bh);
        bias[i] = bb[n & 255] * (n < 512 ? LOG2E : 2.f * LOG2E);
    }
    u32x2* Xout = (u32x2*)((char*)ws + X_OFF);
    for (int u = 0; u < 16; ++u) {
        int unit = blockIdx.x * 16 + u;         // unit = t*16 + g
        int t = unit >> 4, g = unit & 15;
        {   // stage 16 rows of x_t as bf16
            int row = th >> 5, seg = th & 31;
            const float* src = x + ((size_t)(g * 16 + row) * SEQ + t) * INPUT + seg * 8;
            f32x4 a = *(const f32x4*)src;
            f32x4 b = *(const f32x4*)(src + 4);
            u16x8 p;
            p[0] = f2bf(a[0]); p[1] = f2bf(a[1]); p[2] = f2bf(a[2]); p[3] = f2bf(a[3]);
            p[4] = f2bf(b[0]); p[5] = f2bf(b[1]); p[6] = f2bf(b[2]); p[7] = f2bf(b[3]);
            *(u16x8*)&Xb[row][seg * 8] = p;
        }
        __syncthreads();
        f32x4 acc[6];
        #pragma unroll
        for (int i = 0; i < 6; ++i) { acc[i][0] = bias[i]; acc[i][1] = bias[i]; acc[i][2] = bias[i]; acc[i][3] = bias[i]; }
        #pragma unroll
        for (int kt = 0; kt < 8; ++kt) {
            s16x8 a = *(const s16x8*)&Xb[lan][kt * 32 + quad * 8];
            #pragma unroll
            for (int i = 0; i < 6; ++i)
                acc[i] = __builtin_amdgcn_mfma_f32_16x16x32_bf16(a, WX[(kt * NT + wave + 8 * i) * 64 + l], acc[i], 0, 0, 0);
        }
        #pragma unroll
        for (int i = 0; i < 6; ++i) {
            int nt = wave + 8 * i;
            u32x2 p;
            p[0] = (unsigned)f2bf(acc[i][0]) | ((unsigned)f2bf(acc[i][1]) << 16);
            p[1] = (unsigned)f2bf(acc[i][2]) | ((unsigned)f2bf(acc[i][3]) << 16);
            Xout[((size_t)unit * NT + nt) * 64 + l] = p;
        }
        __syncthreads();
    }
}

// ---------------- recurrence ----------------
// 16 WGs x 256 thr (4 waves, 1 wave/SIMD, 512-reg budget).
// Wave w owns nt triples {4w+i, 16+4w+i, 32+4w+i}: r,z,cand for the SAME columns
// -> z and h stay in registers. 96 weight frags = 384 VGPR, truly resident.
__global__ __launch_bounds__(256, 1) void gru_rec_k(
    const float* __restrict__ bo,
    unsigned short* __restrict__ ws,
    float* __restrict__ out)
{
    __shared__ __align__(16) unsigned short Hb[16][264];   // h (bf16, MFMA A)
    __shared__ __align__(16) unsigned short RHb[16][264];  // r*h (bf16, MFMA A)
    const int th = threadIdx.x, wave = th >> 6, l = th & 63, quad = l >> 4, lan = l & 15;
    const int g = blockIdx.x;
    const s16x8* WH = (const s16x8*)((char*)ws + WH_OFF);
    s16x8 wfr[4][8], wfz[4][8], wfc[4][8];                 // 96 frags = 384 VGPR
    #pragma unroll
    for (int i = 0; i < 4; ++i) {
        int ntr = 4 * wave + i;
        #pragma unroll
        for (int kt = 0; kt < 8; ++kt) {
            wfr[i][kt] = WH[(kt * NT + ntr) * 64 + l];
            wfz[i][kt] = WH[(kt * NT + 16 + ntr) * 64 + l];
            wfc[i][kt] = WH[(kt * NT + 32 + ntr) * 64 + l];
        }
    }
    for (int idx = th; idx < 16 * 264; idx += 256) ((unsigned short*)Hb)[idx] = 0;
    float h[4][4];
    #pragma unroll
    for (int i = 0; i < 4; ++i)
        #pragma unroll
        for (int r = 0; r < 4; ++r) h[i][r] = 0.f;

    const u32x2* Xp = (const u32x2*)((char*)ws + X_OFF);
    u32x2 xc[12];                                          // current-step X frags
    {
        const u32x2* X0 = Xp + (size_t)g * NT * 64;        // t = 0
        #pragma unroll
        for (int i = 0; i < 4; ++i) {
            xc[i]     = X0[(size_t)(4 * wave + i) * 64 + l];
            xc[4 + i] = X0[(size_t)(16 + 4 * wave + i) * 64 + l];
            xc[8 + i] = X0[(size_t)(32 + 4 * wave + i) * 64 + l];
        }
    }
    __syncthreads();

    for (int t = 0; t < SEQ; ++t) {
        int tn = (t + 1 < SEQ) ? t + 1 : t;
        const u32x2* Xn = Xp + ((size_t)(tn * 16 + g)) * NT * 64;

        // ---- phase A: r,z preacts; A = h(prev) ----
        f32x4 ar[4], az[4];
        #pragma unroll
        for (int i = 0; i < 4; ++i) { ar[i] = cvt4(xc[i]); az[i] = cvt4(xc[4 + i]); }
        #pragma unroll
        for (int i = 0; i < 4; ++i) {                      // prefetch t+1 r/z X (hidden 1 step)
            xc[i]     = Xn[(size_t)(4 * wave + i) * 64 + l];
            xc[4 + i] = Xn[(size_t)(16 + 4 * wave + i) * 64 + l];
        }
        #pragma unroll
        for (int kt = 0; kt < 8; ++kt) {
            s16x8 a = *(const s16x8*)&Hb[lan][kt * 32 + quad * 8];
            #pragma unroll
            for (int i = 0; i < 4; ++i) {
                ar[i] = __builtin_amdgcn_mfma_f32_16x16x32_bf16(a, wfr[i][kt], ar[i], 0, 0, 0);
                az[i] = __builtin_amdgcn_mfma_f32_16x16x32_bf16(a, wfz[i][kt], az[i], 0, 0, 0);
            }
        }
        float zf[4][4];
        #pragma unroll
        for (int i = 0; i < 4; ++i) {
            int col = (4 * wave + i) * 16 + lan;
            #pragma unroll
            for (int r = 0; r < 4; ++r) {
                zf[i][r] = RCPF(1.f + EXP2F(-az[i][r]));   // sigmoid (weights exp2-scaled)
                float rg = RCPF(1.f + EXP2F(-ar[i][r]));
                RHb[quad * 4 + r][col] = f2bf_fast(rg * h[i][r]);
            }
        }
        __syncthreads();

        // ---- phase B: candidate; A = r*h ----
        f32x4 ac[4];
        #pragma unroll
        for (int i = 0; i < 4; ++i) ac[i] = cvt4(xc[8 + i]);
        #pragma unroll
        for (int i = 0; i < 4; ++i)                        // prefetch t+1 cand X
            xc[8 + i] = Xn[(size_t)(32 + 4 * wave + i) * 64 + l];
        #pragma unroll
        for (int kt = 0; kt < 8; ++kt) {
            s16x8 a = *(const s16x8*)&RHb[lan][kt * 32 + quad * 8];
            #pragma unroll
            for (int i = 0; i < 4; ++i)
                ac[i] = __builtin_amdgcn_mfma_f32_16x16x32_bf16(a, wfc[i][kt], ac[i], 0, 0, 0);
        }
        #pragma unroll
        for (int i = 0; i < 4; ++i) {
            int col = (4 * wave + i) * 16 + lan;
            #pragma unroll
            for (int r = 0; r < 4; ++r) {
                float e  = EXP2F(ac[i][r]);                // = exp(2*preact): weights 2*log2e-scaled
                float hc = (e - 1.f) * RCPF(e + 1.f);      // tanh
                float hn = zf[i][r] * (h[i][r] - hc) + hc; // z*h + (1-z)*hc
                h[i][r] = hn;
                Hb[quad * 4 + r][col] = f2bf_fast(hn);
            }
        }
        __syncthreads();
    }

    // ---- epilogue: out = h_last @ Wo + bo ----
    const s16x8* WO = (const s16x8*)((char*)ws + WO_OFF);
    #pragma unroll
    for (int i = 0; i < 4; ++i) {
        int nt = 4 * wave + i;
        int col = nt * 16 + lan;
        float bv = bo[col];
        f32x4 acc;
        acc[0] = bv; acc[1] = bv; acc[2] = bv; acc[3] = bv;
        #pragma unroll
        for (int kt = 0; kt < 8; ++kt) {
            s16x8 a = *(const s16x8*)&Hb[lan][kt * 32 + quad * 8];
            acc = __builtin_amdgcn_mfma_f32_16x16x32_bf16(a, WO[(kt * NT_O + nt) * 64 + l], acc, 0, 0, 0);
        }
        #pragma unroll
        for (int r = 0; r < 4; ++r)
            out[(size_t)(g * 16 + quad * 4 + r) * 256 + col] = acc[r];
    }
}

// ---------------- round-1 fallback ----------------
__global__ __launch_bounds__(256) void prep_weights_k(
    const float* __restrict__ Wr, const float* __restrict__ Wz,
    const float* __restrict__ Wh, unsigned short* __restrict__ W16)
{
    const int n = DTOT * HIDDEN;
    int idx = blockIdx.x * 256 + threadIdx.x;
    if (idx >= 3 * n) return;
    int m = idx / n;
    int r = idx - m * n;
    const float* src = (m == 0) ? Wr : ((m == 1) ? Wz : Wh);
    W16[idx] = f2bf(src[r]);
}
__device__ __forceinline__ float ldw(const unsigned short* p) { return bf2f(*p); }
__device__ __forceinline__ float ldw(const float* p)          { return *p; }

template <typename WT>
__global__ __launch_bounds__(256) void gru_seq_k(
    const float* __restrict__ x,
    const WT* __restrict__ Wr, const WT* __restrict__ Wz, const WT* __restrict__ Wh,
    const float* __restrict__ br, const float* __restrict__ bz, const float* __restrict__ bh,
    const float* __restrict__ Wo, const float* __restrict__ bo,
    float* __restrict__ out)
{
    const int b = blockIdx.x, j = threadIdx.x;
    __shared__ float xh[DTOT];
    __shared__ float xrh[DTOT];
    xh[INPUT + j] = 0.0f;
    const float brj = br[j], bzj = bz[j], bhj = bh[j];
    const float* xb = x + (size_t)b * SEQ * INPUT;
    const WT* wrj = Wr + j;
    const WT* wzj = Wz + j;
    const WT* whj = Wh + j;
    __syncthreads();
    for (int t = 0; t < SEQ; ++t) {
        float xv = xb[t * INPUT + j];
        xh[j] = xv; xrh[j] = xv;
        __syncthreads();
        float ar = brj, az = bzj;
        #pragma unroll 8
        for (int k = 0; k < DTOT; ++k) {
            float v = xh[k];
            ar += v * ldw(wrj + k * HIDDEN);
            az += v * ldw(wzj + k * HIDDEN);
        }
        float rg = 1.0f / (1.0f + __expf(-ar));
        float zg = 1.0f / (1.0f + __expf(-az));
        float hj = xh[INPUT + j];
        xrh[INPUT + j] = rg * hj;
        __syncthreads();
        float ah = bhj;
        #pragma unroll 8
        for (int k = 0; k < DTOT; ++k) ah += xrh[k] * ldw(whj + k * HIDDEN);
        float hc = tanhf(ah);
        float hn = zg * hj + (1.0f - zg) * hc;
        xh[INPUT + j] = hn;
        __syncthreads();
    }
    float acc = bo[j];
    #pragma unroll 8
    for (int k = 0; k < HIDDEN; ++k) acc += xh[INPUT + k] * Wo[k * HIDDEN + j];
    out[(size_t)b * HIDDEN + j] = acc;
}

extern "C" void kernel_launch(void* const* d_in, const int* in_sizes, int n_in,
                              void* d_out, int out_size, void* d_ws, size_t ws_size,
                              hipStream_t stream) {
    const float* x  = (const float*)d_in[0];
    const float* Wr = (const float*)d_in[1];
    const float* br = (const float*)d_in[2];
    const float* Wz = (const float*)d_in[3];
    const float* bz = (const float*)d_in[4];
    const float* Wh = (const float*)d_in[5];
    const float* bh = (const float*)d_in[6];
    const float* Wo = (const float*)d_in[7];
    const float* bo = (const float*)d_in[8];
    float* out = (float*)d_out;

    if (ws_size >= WS_NEED) {
        unsigned short* ws = (unsigned short*)d_ws;
        pack_weights_k<<<224, 256, 0, stream>>>(Wr, Wz, Wh, Wo, ws);
        xgemm_k<<<512, 512, 0, stream>>>(x, br, bz, bh, ws);
        gru_rec_k<<<16, 256, 0, stream>>>(bo, ws, out);
    } else if (ws_size >= WS_NEED_OLD) {
        unsigned short* W16 = (unsigned short*)d_ws;
        const size_t n = (size_t)DTOT * HIDDEN;
        prep_weights_k<<<(int)((3 * n + 255) / 256), 256, 0, stream>>>(Wr, Wz, Wh, W16);
        gru_seq_k<unsigned short><<<BATCH, 256, 0, stream>>>(
            x, W16, W16 + n, W16 + 2 * n, br, bz, bh, Wo, bo, out);
    } else {
        gru_seq_k<float><<<BATCH, 256, 0, stream>>>(
            x, Wr, Wz, Wh, br, bz, bh, Wo, bo, out);
    }
}